// Round 22
// baseline (136.276 us; speedup 1.0000x reference)
//
#include <hip/hip_runtime.h>

// ---------------- problem constants ----------------
#define BATCH   65536
#define NPAGES  4096
#define KD      128

// ws layout (bytes). Total 18,309,120 B (~17.5 MB).
#define OFF_Q    0u          // (unused after MLP fusion)
#define OFF_K    16777216u   // K bf16 FRAG-PACKED [128 tiles][8 ks][64 lanes]*16B  1 MB
#define OFF_V    17825792u   // V-fragA [256 g][64 lanes]*16B (vcols 0-31)    256 KB
#define OFF_VB   18087936u   // V-fragB compact [256 g][32]*16B (vcols 32-47+aug) 128 KB
#define OFF_W1T  18219008u   // W1^T bf16 [256][48] (k padded 36->48)          24 KB
#define OFF_W2T  18243584u   // W2^T bf16 [128][256]                           64 KB
#define WS_NEEDED 18309120u

typedef short          bfr8   __attribute__((ext_vector_type(8)));
typedef unsigned short u16x8  __attribute__((ext_vector_type(8)));
typedef unsigned short u16x4  __attribute__((ext_vector_type(4)));
typedef unsigned int   u32x4  __attribute__((ext_vector_type(4)));
typedef float          f32x4g __attribute__((ext_vector_type(4)));
typedef float          f32x16v __attribute__((ext_vector_type(16)));

__device__ __forceinline__ unsigned short f2bf(float x){
  unsigned int u = __builtin_bit_cast(unsigned int, x);
  unsigned int r = (u + 0x7fffu + ((u >> 16) & 1u)) >> 16;   // RNE
  return (unsigned short)r;
}
__device__ __forceinline__ float sigmoidf_(float x){ return 1.0f / (1.0f + __expf(-x)); }

__device__ __forceinline__ f32x16v mfma32(bfr8 a, bfr8 b, f32x16v c){
  return __builtin_amdgcn_mfma_f32_32x32x16_bf16(a, b, c, 0, 0, 0);
}
__device__ __forceinline__ f32x16v zero16(){
  f32x16v v;
  #pragma unroll
  for (int i = 0; i < 16; ++i) v[i] = 0.f;
  return v;
}

// Single-fma Schraudolph exp2 -> bf16, pair-packed (attention P).
// F = fma(s, 128, 1.5*2^23 + B/2^16) lands in [2^23,2^24) where ulp=1, so
// mantissa bits [0:15] of F == round(s*128 + B') == the bf16 word of exp2(s).
__device__ __forceinline__ void tile_pack(const f32x16v& s, bfr8& paA, bfr8& paB){
  const float SC = 128.0f;
  const float MG = 12599164.0f;       // 1.5*2^23 + ((127<<23)-294336)/65536
  unsigned w[8];
  #pragma unroll
  for (int p = 0; p < 8; ++p){
    float fa = fmaf(s[2*p],   SC, MG);
    float fb = fmaf(s[2*p+1], SC, MG);
    unsigned ua = __builtin_bit_cast(unsigned, fa);
    unsigned ub = __builtin_bit_cast(unsigned, fb);
    w[p] = __builtin_amdgcn_perm(ub, ua, 0x05040100u);  // lo16=ua.lo16, hi16=ub.lo16
  }
  asm("v_permlane32_swap_b32 %0, %1" : "+v"(w[0]), "+v"(w[2]));
  asm("v_permlane32_swap_b32 %0, %1" : "+v"(w[1]), "+v"(w[3]));
  asm("v_permlane32_swap_b32 %0, %1" : "+v"(w[4]), "+v"(w[6]));
  asm("v_permlane32_swap_b32 %0, %1" : "+v"(w[5]), "+v"(w[7]));
  u32x4 t0 = {w[0], w[1], w[2], w[3]};
  u32x4 t1 = {w[4], w[5], w[6], w[7]};
  paA = __builtin_bit_cast(bfr8, t0);
  paB = __builtin_bit_cast(bfr8, t1);
}

// Plain C-layout -> fragment pack (no exp): cvt_pk_bf16 + permlane32_swap.
__device__ __forceinline__ void pack_raw(const f32x16v& s, bfr8& paA, bfr8& paB){
  unsigned w[8];
  #pragma unroll
  for (int p = 0; p < 8; ++p)
    asm("v_cvt_pk_bf16_f32 %0, %1, %2" : "=v"(w[p]) : "v"(s[2*p]), "v"(s[2*p+1]));
  asm("v_permlane32_swap_b32 %0, %1" : "+v"(w[0]), "+v"(w[2]));
  asm("v_permlane32_swap_b32 %0, %1" : "+v"(w[1]), "+v"(w[3]));
  asm("v_permlane32_swap_b32 %0, %1" : "+v"(w[4]), "+v"(w[6]));
  asm("v_permlane32_swap_b32 %0, %1" : "+v"(w[5]), "+v"(w[7]));
  u32x4 t0 = {w[0], w[1], w[2], w[3]};
  u32x4 t1 = {w[4], w[5], w[6], w[7]};
  paA = __builtin_bit_cast(bfr8, t0);
  paB = __builtin_bit_cast(bfr8, t1);
}

// ---------------- prep: bf16 conversions / layouts ----------------
// 135168 threads (528 x 256), exact segments.
__global__ void prep_kernel(const float* __restrict__ mappings, const float* __restrict__ keys,
                            const float* __restrict__ perms, const float* __restrict__ W1,
                            const float* __restrict__ W2, char* __restrict__ ws){
  int t = blockIdx.x * 256 + threadIdx.x;
  if (t < 65536){                       // K frag-packed: page p, dim-octet c8
    int p = t >> 4, c8 = t & 15;
    const float* src = keys + (size_t)p * 128 + c8 * 8;
    u16x8 val;
    #pragma unroll
    for (int j = 0; j < 8; ++j) val[j] = f2bf(src[j]);
    int ks = c8 >> 1, hi2 = c8 & 1;
    int t32 = p >> 5, lo = p & 31;
    *(u16x8*)(ws + OFF_K + (((size_t)t32 * 8 + ks) * 64 + hi2 * 32 + lo) * 16) = val;
  } else if (t < 65536 + 12288){        // W1^T [256][48], k>=36 zero
    int i = t - 65536; int cc = i / 48, k = i - cc * 48;
    float v = (k < 36) ? W1[(size_t)k * 256 + cc] : 0.0f;
    ((unsigned short*)(ws + OFF_W1T))[cc * 48 + k] = f2bf(v);
  } else if (t < 65536 + 12288 + 32768){ // W2^T [128][256]
    int i = t - (65536 + 12288); int cc = i >> 8, k = i & 255;
    ((unsigned short*)(ws + OFF_W2T))[cc * 256 + k] = f2bf(W2[(size_t)k * 128 + cc]);
  } else if (t < 110592 + 16384){       // V-fragA: vcols 0..31 (all < 36 -> mappings)
    int i = t - 110592;
    int g = i >> 6, lane = i & 63, lo = lane & 31, hi = lane >> 5;
    u16x8 val;
    #pragma unroll
    for (int j = 0; j < 8; ++j){
      int p = 16 * g + 8 * hi + j;
      val[j] = f2bf(mappings[(size_t)p * 72 + 36 + lo]);
    }
    *(u16x8*)(ws + OFF_V + (size_t)i * 16) = val;
  } else {                              // V-fragB compact: vcols 32..47 (aug col 40 = ones)
    int i = t - 126976;                 // [0, 8192)
    int g = i >> 5, idx = i & 31, hi = idx >> 4, l4 = idx & 15;
    int vcol = 32 + l4;
    u16x8 val;
    #pragma unroll
    for (int j = 0; j < 8; ++j){
      int p = 16 * g + 8 * hi + j;
      float v;
      if (vcol < 36)       v = mappings[(size_t)p * 72 + 36 + vcol];
      else if (vcol < 40)  v = perms[(size_t)p * 4 + (vcol - 36)];
      else if (vcol == 40) v = 1.0f;
      else                 v = 0.0f;
      val[j] = f2bf(v);
    }
    *(u16x8*)(ws + OFF_VB + (size_t)i * 16) = val;
  }
}

// ---------------- fused MLP + K-split-4 LDS-free attention ------------------
// 1024 WGs x 256 thr (4 waves), 64 rows/WG. Waves = 4 K-quarters of the SAME
// dual-tile row pair -> 4096 waves = 16/CU supply. MLP on waves 0-1 only
// (in-register, 32 rows each); Q via 16KB swizzled LDS to all waves. K-loop:
// R20's LDS-free direct-register loads (frag-packed K, L2-resident), 32 iters
// per wave over its quarter; no barriers, no staging. 4-partial LDS combine.
__global__ __launch_bounds__(256, 2) void attn_kernel(const float* __restrict__ vab,
    const float* __restrict__ b1, const float* __restrict__ b2,
    const float* __restrict__ temp_p, const char* __restrict__ ws,
    float* __restrict__ out){
  __shared__ __align__(16) char smem[33792];    // Q (16K) -> combine (33K)

  const int tid = threadIdx.x;
  const int lane = tid & 63, wv = tid >> 6;     // wv = K-quarter
  const int lo = lane & 31, hi = lane >> 5;
  const int bb = blockIdx.x * 64;

  const unsigned short* w1t = (const unsigned short*)(ws + OFF_W1T);
  const unsigned short* w2t = (const unsigned short*)(ws + OFF_W2T);
  const float qscale = 1.44269504088896f / fmaxf(fabsf(temp_p[0]), 0.1f);

  // offset-bit passthrough for the WG's 64 rows
  for (int i = tid; i < 64 * 12; i += 256){
    int r = i / 12, c = i - r * 12;
    out[(size_t)(bb + r) * 52 + c] = vab[(size_t)(bb + r) * 48 + c];
  }

  // ---- MLP stage: waves 0-1 only (wave wv owns rows bb+wv*32 .. +32) ------
  if (wv < 2){
    bfr8 hfrag[16];                             // h B-frags (k=hcol), 64 VGPR
    const float* vrow = vab + (size_t)(bb + wv * 32 + lo) * 48 + 12;
    bfr8 pbf[3];
    #pragma unroll
    for (int ks = 0; ks < 2; ++ks){
      f32x4g a = *(const f32x4g*)(vrow + 16 * ks + 8 * hi);
      f32x4g b = *(const f32x4g*)(vrow + 16 * ks + 8 * hi + 4);
      bfr8 f;
      f[0]=(short)f2bf(a[0]); f[1]=(short)f2bf(a[1]); f[2]=(short)f2bf(a[2]); f[3]=(short)f2bf(a[3]);
      f[4]=(short)f2bf(b[0]); f[5]=(short)f2bf(b[1]); f[6]=(short)f2bf(b[2]); f[7]=(short)f2bf(b[3]);
      pbf[ks] = f;
    }
    {   // ks=2: dims 32..39 (hi=0, j<4 valid) / 40..47 (hi=1, all zero-pad)
      bfr8 f;
      #pragma unroll
      for (int j = 0; j < 8; ++j) f[j] = 0;
      if (hi == 0){
        f32x4g a = *(const f32x4g*)(vrow + 32);
        f[0]=(short)f2bf(a[0]); f[1]=(short)f2bf(a[1]); f[2]=(short)f2bf(a[2]); f[3]=(short)f2bf(a[3]);
      }
      pbf[2] = f;
    }

    // phase 1: per 32-hcol tile: h^T = W1^T @ pb^T; gelu; pack -> hfrag
    #pragma unroll
    for (int art = 0; art < 8; ++art){
      const int hcol0 = art * 32;
      f32x16v acc = zero16();
      #pragma unroll
      for (int ks = 0; ks < 3; ++ks){
        bfr8 af = *(const bfr8*)(w1t + (size_t)(hcol0 + lo) * 48 + 8 * hi + 16 * ks);
        acc = mfma32(af, pbf[ks], acc);
      }
      #pragma unroll
      for (int w = 0; w < 4; ++w){
        f32x4g b1g = *(const f32x4g*)(b1 + hcol0 + 8 * w + 4 * hi);
        #pragma unroll
        for (int rs = 0; rs < 4; ++rs){
          float x = acc[4 * w + rs] + b1g[rs];
          float u = x * (0.7978845608028654f + 0.0356774081f * x * x);
          float t = exp2f(u * -2.885390081777927f);   // e^{-2u}
          float th = (1.0f - t) / (1.0f + t);
          acc[4 * w + rs] = 0.5f * x * (1.0f + th);   // tanh-form gelu
        }
      }
      pack_raw(acc, hfrag[2 * art], hfrag[2 * art + 1]);
    }

    // phase 2: q^T = W2^T @ h^T (h in regs) -> qlds bf16 (folded invt*log2e)
    const int qrow = wv * 32 + lo;
    #pragma unroll
    for (int qt = 0; qt < 4; ++qt){
      const int qcol0 = qt * 32;
      f32x16v acc = zero16();
      #pragma unroll
      for (int ks = 0; ks < 16; ++ks){
        bfr8 af2 = *(const bfr8*)(w2t + (size_t)(qcol0 + lo) * 256 + 8 * hi + 16 * ks);
        acc = mfma32(af2, hfrag[ks], acc);
      }
      #pragma unroll
      for (int w = 0; w < 4; ++w){
        f32x4g b2g = *(const f32x4g*)(b2 + qcol0 + 8 * w + 4 * hi);
        u16x4 pk;
        #pragma unroll
        for (int rs = 0; rs < 4; ++rs)
          pk[rs] = f2bf((acc[4 * w + rs] + b2g[rs]) * qscale);
        int qs2 = (qcol0 + 8 * w + 4 * hi) * 2;
        *(u16x4*)(smem + qrow * 256 + (qs2 ^ ((qrow & 15) << 4))) = pk;
      }
    }
  }
  __syncthreads();

  // ---- all waves read the SAME Q fragments (B-frag: col=lo) ---------------
  bfr8 qfA[8], qfB[8];
  {
    const int rA = lo, rB = 32 + lo;
    #pragma unroll
    for (int ks = 0; ks < 8; ++ks){
      qfA[ks] = *(const bfr8*)(smem + rA * 256 + ((32 * ks + 16 * hi) ^ ((rA & 15) << 4)));
      qfB[ks] = *(const bfr8*)(smem + rB * 256 + ((32 * ks + 16 * hi) ^ ((rB & 15) << 4)));
    }
  }

  // ---- attention K-loop: pure register dataflow over this wave's quarter --
  const char* kf = ws + OFF_K;
  const char* va = ws + OFF_V;
  const char* vb = ws + OFF_VB;

  f32x16v accA0 = zero16(), accA1 = zero16();
  f32x16v accB0 = zero16(), accB1 = zero16();

  const int gb = wv * 32;                       // first 32-page tile of quarter
  const int vbo = (hi * 16 + (lo & 15)) * 16;   // fragB lane offset (2-way broadcast)

  #pragma unroll 2
  for (int c = 0; c < 32; ++c){
    const int t2 = gb + c;                      // 32-page tile index
    const char* kp = kf + (size_t)t2 * 8192 + lane * 16;

    bfr8 k[8];
    #pragma unroll
    for (int ks = 0; ks < 8; ++ks) k[ks] = *(const bfr8*)(kp + ks * 1024);

    const char* vg  = va + (size_t)t2 * 2048 + lane * 16;
    const char* vgb = vb + (size_t)t2 * 1024 + vbo;
    bfr8 v00 = *(const bfr8*)(vg);              // pages 0-15, vcols 0-31
    bfr8 v01 = *(const bfr8*)(vg + 1024);       // pages 16-31
    bfr8 v10 = *(const bfr8*)(vgb);             // pages 0-15, vcols 32-47(+aug)
    bfr8 v11 = *(const bfr8*)(vgb + 512);       // pages 16-31

    f32x16v sA = zero16(), sB = zero16();
    __builtin_amdgcn_s_setprio(1);
    #pragma unroll
    for (int ks = 0; ks < 8; ++ks){
      sA = mfma32(k[ks], qfA[ks], sA);
      sB = mfma32(k[ks], qfB[ks], sB);
    }
    __builtin_amdgcn_s_setprio(0);

    bfr8 p0, p1, p2, p3;
    tile_pack(sA, p0, p1);
    tile_pack(sB, p2, p3);
    __builtin_amdgcn_s_setprio(1);
    accA0 = mfma32(p0, v00, accA0);  accA0 = mfma32(p1, v01, accA0);
    accA1 = mfma32(p0, v10, accA1);  accA1 = mfma32(p1, v11, accA1);
    accB0 = mfma32(p2, v00, accB0);  accB0 = mfma32(p3, v01, accB0);
    accB1 = mfma32(p2, v10, accB1);  accB1 = mfma32(p3, v11, accB1);
    __builtin_amdgcn_s_setprio(0);
  }

  // ---- combine 4 quarter-partials via LDS (Q region dead) -----------------
  __syncthreads();
  float* comb0 = (float*)smem;                  // [3][64][32] f32, 24 KB
  float* comb1 = (float*)(smem + 24576);        // [3][64][12] f32,  9 KB
  if (wv > 0){
    const int b0 = (wv - 1) * 2048, b1o = (wv - 1) * 768;
    #pragma unroll
    for (int r = 0; r < 16; ++r){
      int rl = (r & 3) + 8 * (r >> 2) + 4 * hi;
      comb0[b0 + rl * 32 + lo] = accA0[r];
      comb0[b0 + (rl + 32) * 32 + lo] = accB0[r];
      if (lo < 9){
        comb1[b1o + rl * 12 + lo] = accA1[r];
        comb1[b1o + (rl + 32) * 12 + lo] = accB1[r];
      }
    }
  }
  __syncthreads();
  if (wv == 0){
    #pragma unroll
    for (int r = 0; r < 16; ++r){
      int rl = (r & 3) + 8 * (r >> 2) + 4 * hi;
      {
        float n0 = accA0[r] + comb0[rl * 32 + lo] + comb0[2048 + rl * 32 + lo]
                            + comb0[4096 + rl * 32 + lo];
        float a1 = accA1[r];
        if (lo < 9) a1 += comb1[rl * 12 + lo] + comb1[768 + rl * 12 + lo]
                        + comb1[1536 + rl * 12 + lo];
        float dn = __shfl(a1, (lane & 32) + 8, 64);   // denom = vcol 40 (lo==8)
        float di = 1.0f / dn;
        size_t q = (size_t)(bb + rl);
        out[q * 52 + 12 + lo] = sigmoidf_(n0 * di);
        if (lo < 8) out[q * 52 + 44 + lo] = sigmoidf_(a1 * di);
      }
      {
        int r2 = rl + 32;
        float n0 = accB0[r] + comb0[r2 * 32 + lo] + comb0[2048 + r2 * 32 + lo]
                            + comb0[4096 + r2 * 32 + lo];
        float a1 = accB1[r];
        if (lo < 9) a1 += comb1[r2 * 12 + lo] + comb1[768 + r2 * 12 + lo]
                        + comb1[1536 + r2 * 12 + lo];
        float dn = __shfl(a1, (lane & 32) + 8, 64);
        float di = 1.0f / dn;
        size_t q = (size_t)(bb + r2);
        out[q * 52 + 12 + lo] = sigmoidf_(n0 * di);
        if (lo < 8) out[q * 52 + 44 + lo] = sigmoidf_(a1 * di);
      }
    }
  }
}

extern "C" void kernel_launch(void* const* d_in, const int* in_sizes, int n_in,
                              void* d_out, int out_size, void* d_ws, size_t ws_size,
                              hipStream_t stream){
  const float* vab      = (const float*)d_in[0];
  const float* mappings = (const float*)d_in[1];
  const float* keys     = (const float*)d_in[2];
  const float* perms    = (const float*)d_in[3];
  const float* W1       = (const float*)d_in[4];
  const float* b1       = (const float*)d_in[5];
  const float* W2       = (const float*)d_in[6];
  const float* b2       = (const float*)d_in[7];
  const float* temp     = (const float*)d_in[8];
  float* out = (float*)d_out;
  char*  ws  = (char*)d_ws;
  if (ws_size < WS_NEEDED) return;   // loud failure instead of OOB corruption

  prep_kernel<<<528, 256, 0, stream>>>(mappings, keys, perms, W1, W2, ws);
  attn_kernel<<<1024, 256, 0, stream>>>(vab, b1, b2, temp, ws, out);
}

// Round 23
// 83.050 us; speedup vs baseline: 1.6409x; 1.6409x over previous
//
#include <hip/hip_runtime.h>

// ---------------- problem constants ----------------
#define BATCH   65536
#define NPAGES  4096
#define KD      128

// ws layout (bytes). Total 18,309,120 B (~17.5 MB). (OFF_Q region unused.)
#define OFF_Q    0u          // (unused after MLP fusion)
#define OFF_K    16777216u   // K bf16, 64-page chunks, XOR-swizzled (r&15)     1 MB
#define OFF_V    17825792u   // V-fragA [256 g][64 lanes]*16B (vcols 0-31)    256 KB
#define OFF_VB   18087936u   // V-fragB compact [256 g][32]*16B (vcols 32-47+aug) 128 KB
#define OFF_W1T  18219008u   // W1^T bf16 [256][48] (k padded 36->48)          24 KB
#define OFF_W2T  18243584u   // W2^T bf16 [128][256]                           64 KB
#define WS_NEEDED 18309120u

typedef short          bfr8   __attribute__((ext_vector_type(8)));
typedef unsigned short u16x8  __attribute__((ext_vector_type(8)));
typedef unsigned short u16x4  __attribute__((ext_vector_type(4)));
typedef unsigned int   u32x4  __attribute__((ext_vector_type(4)));
typedef float          f32x4g __attribute__((ext_vector_type(4)));
typedef float          f32x16v __attribute__((ext_vector_type(16)));

__device__ __forceinline__ unsigned short f2bf(float x){
  unsigned int u = __builtin_bit_cast(unsigned int, x);
  unsigned int r = (u + 0x7fffu + ((u >> 16) & 1u)) >> 16;   // RNE
  return (unsigned short)r;
}
__device__ __forceinline__ float sigmoidf_(float x){ return 1.0f / (1.0f + __expf(-x)); }

__device__ __forceinline__ f32x16v mfma32(bfr8 a, bfr8 b, f32x16v c){
  return __builtin_amdgcn_mfma_f32_32x32x16_bf16(a, b, c, 0, 0, 0);
}
__device__ __forceinline__ f32x16v zero16(){
  f32x16v v;
  #pragma unroll
  for (int i = 0; i < 16; ++i) v[i] = 0.f;
  return v;
}

// async global->LDS, 16B per lane, dest = ldsbase + lane*16 (linear, preserves pre-swizzle)
__device__ __forceinline__ void glds16(const void* g, void* l){
  __builtin_amdgcn_global_load_lds(
      (const __attribute__((address_space(1))) unsigned int*)g,
      (__attribute__((address_space(3))) unsigned int*)l, 16, 0, 0);
}

// Single-fma Schraudolph exp2 -> bf16, pair-packed (attention P).
// F = fma(s, 128, 1.5*2^23 + B/2^16) lands in [2^23,2^24) where ulp=1, so
// mantissa bits [0:15] of F == round(s*128 + B') == the bf16 word of exp2(s).
__device__ __forceinline__ void tile_pack(const f32x16v& s, bfr8& paA, bfr8& paB){
  const float SC = 128.0f;
  const float MG = 12599164.0f;       // 1.5*2^23 + ((127<<23)-294336)/65536
  unsigned w[8];
  #pragma unroll
  for (int p = 0; p < 8; ++p){
    float fa = fmaf(s[2*p],   SC, MG);
    float fb = fmaf(s[2*p+1], SC, MG);
    unsigned ua = __builtin_bit_cast(unsigned, fa);
    unsigned ub = __builtin_bit_cast(unsigned, fb);
    w[p] = __builtin_amdgcn_perm(ub, ua, 0x05040100u);  // lo16=ua.lo16, hi16=ub.lo16
  }
  asm("v_permlane32_swap_b32 %0, %1" : "+v"(w[0]), "+v"(w[2]));
  asm("v_permlane32_swap_b32 %0, %1" : "+v"(w[1]), "+v"(w[3]));
  asm("v_permlane32_swap_b32 %0, %1" : "+v"(w[4]), "+v"(w[6]));
  asm("v_permlane32_swap_b32 %0, %1" : "+v"(w[5]), "+v"(w[7]));
  u32x4 t0 = {w[0], w[1], w[2], w[3]};
  u32x4 t1 = {w[4], w[5], w[6], w[7]};
  paA = __builtin_bit_cast(bfr8, t0);
  paB = __builtin_bit_cast(bfr8, t1);
}

// Plain C-layout -> fragment pack (no exp): cvt_pk_bf16 + permlane32_swap.
__device__ __forceinline__ void pack_raw(const f32x16v& s, bfr8& paA, bfr8& paB){
  unsigned w[8];
  #pragma unroll
  for (int p = 0; p < 8; ++p)
    asm("v_cvt_pk_bf16_f32 %0, %1, %2" : "=v"(w[p]) : "v"(s[2*p]), "v"(s[2*p+1]));
  asm("v_permlane32_swap_b32 %0, %1" : "+v"(w[0]), "+v"(w[2]));
  asm("v_permlane32_swap_b32 %0, %1" : "+v"(w[1]), "+v"(w[3]));
  asm("v_permlane32_swap_b32 %0, %1" : "+v"(w[4]), "+v"(w[6]));
  asm("v_permlane32_swap_b32 %0, %1" : "+v"(w[5]), "+v"(w[7]));
  u32x4 t0 = {w[0], w[1], w[2], w[3]};
  u32x4 t1 = {w[4], w[5], w[6], w[7]};
  paA = __builtin_bit_cast(bfr8, t0);
  paB = __builtin_bit_cast(bfr8, t1);
}

// ---------------- prep: bf16 conversions / layouts ----------------
// 135168 threads (528 x 256), exact segments.
__global__ void prep_kernel(const float* __restrict__ mappings, const float* __restrict__ keys,
                            const float* __restrict__ perms, const float* __restrict__ W1,
                            const float* __restrict__ W2, char* __restrict__ ws){
  int t = blockIdx.x * 256 + threadIdx.x;
  if (t < 65536){                       // K: 4096 pages x 16 granules of 8 cols
    int p = t >> 4, c8 = t & 15;
    const float* src = keys + (size_t)p * 128 + c8 * 8;
    u16x8 val;
    #pragma unroll
    for (int j = 0; j < 8; ++j) val[j] = f2bf(src[j]);
    int r = p & 63, chunk = p >> 6;
    int byteoff = (r * 256 + c8 * 16) ^ ((r & 15) << 4);  // 16-slot swizzle: 2-way max
    *(u16x8*)(ws + OFF_K + (size_t)chunk * 16384 + byteoff) = val;
  } else if (t < 65536 + 12288){        // W1^T [256][48], k>=36 zero
    int i = t - 65536; int cc = i / 48, k = i - cc * 48;
    float v = (k < 36) ? W1[(size_t)k * 256 + cc] : 0.0f;
    ((unsigned short*)(ws + OFF_W1T))[cc * 48 + k] = f2bf(v);
  } else if (t < 65536 + 12288 + 32768){ // W2^T [128][256]
    int i = t - (65536 + 12288); int cc = i >> 8, k = i & 255;
    ((unsigned short*)(ws + OFF_W2T))[cc * 256 + k] = f2bf(W2[(size_t)k * 128 + cc]);
  } else if (t < 110592 + 16384){       // V-fragA: vcols 0..31 (all < 36 -> mappings)
    int i = t - 110592;
    int g = i >> 6, lane = i & 63, lo = lane & 31, hi = lane >> 5;
    u16x8 val;
    #pragma unroll
    for (int j = 0; j < 8; ++j){
      int p = 16 * g + 8 * hi + j;
      val[j] = f2bf(mappings[(size_t)p * 72 + 36 + lo]);
    }
    *(u16x8*)(ws + OFF_V + (size_t)i * 16) = val;
  } else {                              // V-fragB compact: vcols 32..47 (aug col 40 = ones)
    int i = t - 126976;                 // [0, 8192)
    int g = i >> 5, idx = i & 31, hi = idx >> 4, l4 = idx & 15;
    int vcol = 32 + l4;
    u16x8 val;
    #pragma unroll
    for (int j = 0; j < 8; ++j){
      int p = 16 * g + 8 * hi + j;
      float v;
      if (vcol < 36)       v = mappings[(size_t)p * 72 + 36 + vcol];
      else if (vcol < 40)  v = perms[(size_t)p * 4 + (vcol - 36)];
      else if (vcol == 40) v = 1.0f;
      else                 v = 0.0f;
      val[j] = f2bf(v);
    }
    *(u16x8*)(ws + OFF_VB + (size_t)i * 16) = val;
  }
}

// ---------------- fused MLP (in-register) + attention, 2-chunk ILP ---------
// 512 WGs x 256 thr (4 waves), 128 rows/WG. MLP as R18/R21. K-loop: per half,
// 4 x 8KB buffers; each iteration computes TWO 32-page groups (4 independent
// QK MFMA chains halve exposed latency) and stages the next two. 16 barriers.
__global__ __launch_bounds__(256, 2) void attn_kernel(const float* __restrict__ vab,
    const float* __restrict__ b1, const float* __restrict__ b2,
    const float* __restrict__ temp_p, const char* __restrict__ ws,
    float* __restrict__ out){
  __shared__ __align__(16) char smem[65536];    // Q (32K) / per-half 4x8K K bufs / combine

  const int tid = threadIdx.x;
  const int lane = tid & 63, wv = tid >> 6;
  const int half = wv >> 1, sub = wv & 1;
  const int lo = lane & 31, hi = lane >> 5;
  const int bb = blockIdx.x * 128;

  const unsigned short* w1t = (const unsigned short*)(ws + OFF_W1T);
  const unsigned short* w2t = (const unsigned short*)(ws + OFF_W2T);
  const float qscale = 1.44269504088896f / fmaxf(fabsf(temp_p[0]), 0.1f);

  // offset-bit passthrough for all 128 rows
  for (int i = tid; i < 128 * 12; i += 256){
    int r = i / 12, c = i - r * 12;
    out[(size_t)(bb + r) * 52 + c] = vab[(size_t)(bb + r) * 48 + c];
  }

  // ---- MLP stage, fully in-register (wave owns rows bb+wv*32 .. +32) ------
  bfr8 hfrag[16];                               // h B-frags (k=hcol), 64 VGPR
  {
    const float* vrow = vab + (size_t)(bb + wv * 32 + lo) * 48 + 12;
    bfr8 pbf[3];
    #pragma unroll
    for (int ks = 0; ks < 2; ++ks){
      f32x4g a = *(const f32x4g*)(vrow + 16 * ks + 8 * hi);
      f32x4g b = *(const f32x4g*)(vrow + 16 * ks + 8 * hi + 4);
      bfr8 f;
      f[0]=(short)f2bf(a[0]); f[1]=(short)f2bf(a[1]); f[2]=(short)f2bf(a[2]); f[3]=(short)f2bf(a[3]);
      f[4]=(short)f2bf(b[0]); f[5]=(short)f2bf(b[1]); f[6]=(short)f2bf(b[2]); f[7]=(short)f2bf(b[3]);
      pbf[ks] = f;
    }
    {   // ks=2: dims 32..39 (hi=0, j<4 valid) / 40..47 (hi=1, all zero-pad)
      bfr8 f;
      #pragma unroll
      for (int j = 0; j < 8; ++j) f[j] = 0;
      if (hi == 0){
        f32x4g a = *(const f32x4g*)(vrow + 32);
        f[0]=(short)f2bf(a[0]); f[1]=(short)f2bf(a[1]); f[2]=(short)f2bf(a[2]); f[3]=(short)f2bf(a[3]);
      }
      pbf[2] = f;
    }

    // phase 1: per 32-hcol tile: h^T = W1^T @ pb^T; gelu; pack -> hfrag
    #pragma unroll
    for (int art = 0; art < 8; ++art){
      const int hcol0 = art * 32;
      f32x16v acc = zero16();
      #pragma unroll
      for (int ks = 0; ks < 3; ++ks){
        bfr8 af = *(const bfr8*)(w1t + (size_t)(hcol0 + lo) * 48 + 8 * hi + 16 * ks);
        acc = mfma32(af, pbf[ks], acc);
      }
      #pragma unroll
      for (int w = 0; w < 4; ++w){
        f32x4g b1g = *(const f32x4g*)(b1 + hcol0 + 8 * w + 4 * hi);
        #pragma unroll
        for (int rs = 0; rs < 4; ++rs){
          float x = acc[4 * w + rs] + b1g[rs];
          float u = x * (0.7978845608028654f + 0.0356774081f * x * x);
          float t = exp2f(u * -2.885390081777927f);   // e^{-2u}
          float th = (1.0f - t) / (1.0f + t);
          acc[4 * w + rs] = 0.5f * x * (1.0f + th);   // tanh-form gelu
        }
      }
      pack_raw(acc, hfrag[2 * art], hfrag[2 * art + 1]);
    }

    // phase 2: q^T = W2^T @ h^T (h in regs) -> qlds bf16 (folded invt*log2e)
    const int qrow = wv * 32 + lo;
    #pragma unroll
    for (int qt = 0; qt < 4; ++qt){
      const int qcol0 = qt * 32;
      f32x16v acc = zero16();
      #pragma unroll
      for (int ks = 0; ks < 16; ++ks){
        bfr8 af2 = *(const bfr8*)(w2t + (size_t)(qcol0 + lo) * 256 + 8 * hi + 16 * ks);
        acc = mfma32(af2, hfrag[ks], acc);
      }
      #pragma unroll
      for (int w = 0; w < 4; ++w){
        f32x4g b2g = *(const f32x4g*)(b2 + qcol0 + 8 * w + 4 * hi);
        u16x4 pk;
        #pragma unroll
        for (int rs = 0; rs < 4; ++rs)
          pk[rs] = f2bf((acc[4 * w + rs] + b2g[rs]) * qscale);
        int qs2 = (qcol0 + 8 * w + 4 * hi) * 2;
        *(u16x4*)(smem + qrow * 256 + (qs2 ^ ((qrow & 15) << 4))) = pk;
      }
    }
  }
  __syncthreads();

  // ---- read Q fragments (B-frag: col=lo), then free LDS for K staging -----
  bfr8 qfA[8], qfB[8];
  {
    const int rA = sub * 64 + lo, rB = sub * 64 + 32 + lo;
    #pragma unroll
    for (int ks = 0; ks < 8; ++ks){
      qfA[ks] = *(const bfr8*)(smem + rA * 256 + ((32 * ks + 16 * hi) ^ ((rA & 15) << 4)));
      qfB[ks] = *(const bfr8*)(smem + rB * 256 + ((32 * ks + 16 * hi) ^ ((rB & 15) << 4)));
    }
  }
  __syncthreads();

  // ---- attention K-loop: dual-tile, 2 groups/iter (4 QK chains) -----------
  const char* kbase = ws + OFF_K;
  const char* va = ws + OFF_V;
  const char* vb = ws + OFF_VB;

  f32x16v accA0 = zero16(), accA1 = zero16();
  f32x16v accB0 = zero16(), accB1 = zero16();

  char* myk = smem + half * 32768;              // this half's 4 x 8 KB buffers
  const int gb = half * 64;                     // first 32-page group index
  const int vbo = (hi * 16 + (lo & 15)) * 16;   // fragB lane offset (2-way broadcast)

  // prologue: stage groups gb+0, gb+1 into bufs 0,1 (each wave covers sub*4KB)
  #pragma unroll
  for (int g = 0; g < 2; ++g)
    #pragma unroll
    for (int i = 0; i < 4; ++i)
      glds16(kbase + (size_t)(gb + g) * 8192 + sub * 4096 + lane * 16 + i * 1024,
             myk + g * 8192 + sub * 4096 + i * 1024);
  __syncthreads();

  for (int cc = 0; cc < 16; ++cc){
    const int c0 = 2 * cc, c1 = 2 * cc + 1;
    if (cc < 15){                               // stage the NEXT two groups
      #pragma unroll
      for (int g = 0; g < 2; ++g){
        const char* src = kbase + (size_t)(gb + c0 + 2 + g) * 8192 + sub * 4096 + lane * 16;
        char* dst = myk + ((c0 + 2 + g) & 3) * 8192 + sub * 4096;
        #pragma unroll
        for (int i = 0; i < 4; ++i) glds16(src + i * 1024, dst + i * 1024);
      }
    }

    const char* kb0 = myk + (c0 & 3) * 8192;
    const char* kb1 = myk + (c1 & 3) * 8192;

    // 4 independent QK chains (halved exposed MFMA latency)
    f32x16v sA0 = zero16(), sB0 = zero16(), sA1 = zero16(), sB1 = zero16();
    __builtin_amdgcn_s_setprio(1);
    #pragma unroll
    for (int ks = 0; ks < 8; ++ks){
      int cb = (32 * ks + 16 * hi) ^ ((lo & 15) << 4);
      bfr8 k0 = *(const bfr8*)(kb0 + lo * 256 + cb);
      bfr8 k1 = *(const bfr8*)(kb1 + lo * 256 + cb);
      sA0 = mfma32(k0, qfA[ks], sA0);
      sB0 = mfma32(k0, qfB[ks], sB0);
      sA1 = mfma32(k1, qfA[ks], sA1);
      sB1 = mfma32(k1, qfB[ks], sB1);
    }
    __builtin_amdgcn_s_setprio(0);

    // tile 0: pack + V + PV
    {
      const int t2 = gb + c0;
      const char* vg  = va + (size_t)t2 * 2048 + lane * 16;
      const char* vgb = vb + (size_t)t2 * 1024 + vbo;
      bfr8 v00 = *(const bfr8*)(vg);
      bfr8 v01 = *(const bfr8*)(vg + 1024);
      bfr8 v10 = *(const bfr8*)(vgb);
      bfr8 v11 = *(const bfr8*)(vgb + 512);
      bfr8 p0, p1, p2, p3;
      tile_pack(sA0, p0, p1);
      tile_pack(sB0, p2, p3);
      __builtin_amdgcn_s_setprio(1);
      accA0 = mfma32(p0, v00, accA0);  accA0 = mfma32(p1, v01, accA0);
      accA1 = mfma32(p0, v10, accA1);  accA1 = mfma32(p1, v11, accA1);
      accB0 = mfma32(p2, v00, accB0);  accB0 = mfma32(p3, v01, accB0);
      accB1 = mfma32(p2, v10, accB1);  accB1 = mfma32(p3, v11, accB1);
      __builtin_amdgcn_s_setprio(0);
    }
    // tile 1: pack + V + PV
    {
      const int t2 = gb + c1;
      const char* vg  = va + (size_t)t2 * 2048 + lane * 16;
      const char* vgb = vb + (size_t)t2 * 1024 + vbo;
      bfr8 v00 = *(const bfr8*)(vg);
      bfr8 v01 = *(const bfr8*)(vg + 1024);
      bfr8 v10 = *(const bfr8*)(vgb);
      bfr8 v11 = *(const bfr8*)(vgb + 512);
      bfr8 p0, p1, p2, p3;
      tile_pack(sA1, p0, p1);
      tile_pack(sB1, p2, p3);
      __builtin_amdgcn_s_setprio(1);
      accA0 = mfma32(p0, v00, accA0);  accA0 = mfma32(p1, v01, accA0);
      accA1 = mfma32(p0, v10, accA1);  accA1 = mfma32(p1, v11, accA1);
      accB0 = mfma32(p2, v00, accB0);  accB0 = mfma32(p3, v01, accB0);
      accB1 = mfma32(p2, v10, accB1);  accB1 = mfma32(p3, v11, accB1);
      __builtin_amdgcn_s_setprio(0);
    }

    __syncthreads();   // drains DMA (vmcnt) + LDS reads; next buffers ready
  }

  // ---- combine halves via LDS overlay (K buffers are dead now) ----
  float* comb0 = (float*)smem;                  // [128][32] f32, 16 KB
  float* comb1 = (float*)(smem + 16384);        // [128][12] f32, 6 KB
  if (half == 1){
    #pragma unroll
    for (int r = 0; r < 16; ++r){
      int rl = sub * 64 + (r & 3) + 8 * (r >> 2) + 4 * hi;
      comb0[rl * 32 + lo] = accA0[r];
      comb0[(rl + 32) * 32 + lo] = accB0[r];
      if (lo < 9){
        comb1[rl * 12 + lo] = accA1[r];
        comb1[(rl + 32) * 12 + lo] = accB1[r];
      }
    }
  }
  __syncthreads();
  if (half == 0){
    #pragma unroll
    for (int r = 0; r < 16; ++r){
      int rl = sub * 64 + (r & 3) + 8 * (r >> 2) + 4 * hi;
      {
        float n0 = accA0[r] + comb0[rl * 32 + lo];
        float a1 = accA1[r] + ((lo < 9) ? comb1[rl * 12 + lo] : 0.0f);
        float dn = __shfl(a1, (lane & 32) + 8, 64);   // denom = vcol 40 (lo==8)
        float di = 1.0f / dn;
        size_t q = (size_t)(bb + rl);
        out[q * 52 + 12 + lo] = sigmoidf_(n0 * di);
        if (lo < 8) out[q * 52 + 44 + lo] = sigmoidf_(a1 * di);
      }
      {
        float n0 = accB0[r] + comb0[(rl + 32) * 32 + lo];
        float a1 = accB1[r] + ((lo < 9) ? comb1[(rl + 32) * 12 + lo] : 0.0f);
        float dn = __shfl(a1, (lane & 32) + 8, 64);
        float di = 1.0f / dn;
        size_t q = (size_t)(bb + rl + 32);
        out[q * 52 + 12 + lo] = sigmoidf_(n0 * di);
        if (lo < 8) out[q * 52 + 44 + lo] = sigmoidf_(a1 * di);
      }
    }
  }
}

extern "C" void kernel_launch(void* const* d_in, const int* in_sizes, int n_in,
                              void* d_out, int out_size, void* d_ws, size_t ws_size,
                              hipStream_t stream){
  const float* vab      = (const float*)d_in[0];
  const float* mappings = (const float*)d_in[1];
  const float* keys     = (const float*)d_in[2];
  const float* perms    = (const float*)d_in[3];
  const float* W1       = (const float*)d_in[4];
  const float* b1       = (const float*)d_in[5];
  const float* W2       = (const float*)d_in[6];
  const float* b2       = (const float*)d_in[7];
  const float* temp     = (const float*)d_in[8];
  float* out = (float*)d_out;
  char*  ws  = (char*)d_ws;
  if (ws_size < WS_NEEDED) return;   // loud failure instead of OOB corruption

  prep_kernel<<<528, 256, 0, stream>>>(mappings, keys, perms, W1, W2, ws);
  attn_kernel<<<512, 256, 0, stream>>>(vab, b1, b2, temp, ws, out);
}